// Round 2
// baseline (265.553 us; speedup 1.0000x reference)
//
#include <hip/hip_runtime.h>

typedef __attribute__((ext_vector_type(4))) float floatx4;
typedef __attribute__((ext_vector_type(8))) short shortx8;

// db4 analysis filters, TRUE-convolution orientation:
// y[m] = sum_i F[i] * xp[2m + 7 - i]  (xp reflect-padded, pl = 6 at every level)
__device__ __constant__ float DLO[8] = {
    -0.010597401784997278f, 0.032883011666982945f,
     0.030841381835986965f, -0.18703481171888114f,
    -0.02798376941698385f,  0.6308807679295904f,
     0.7148465705525415f,   0.23037781330885523f};
__device__ __constant__ float DHI[8] = {
    -0.23037781330885523f,  0.7148465705525415f,
    -0.6308807679295904f,  -0.02798376941698385f,
     0.18703481171888114f,  0.030841381835986965f,
     0.032883011666982945f, -0.010597401784997278f};

__device__ __forceinline__ unsigned short f2bf_rne(float f) {
  unsigned u = __builtin_bit_cast(unsigned, f);
  unsigned r = (u + 0x7FFFu + ((u >> 16) & 1u)) >> 16;
  return (unsigned short)r;
}

// One analysis filter-bank level. pl (left reflect pad) == 6 for n in {64,35,21}.
template <int N, int OUT>
__device__ __forceinline__ void afb(const float* x, float* lo, float* hi) {
#pragma unroll
  for (int m = 0; m < OUT; ++m) {
    float aL = 0.f, aH = 0.f;
#pragma unroll
    for (int i = 0; i < 8; ++i) {
      int s = 2 * m + 1 - i;              // 2m + 7 - i - 6
      s = (s < 0) ? -s : s;               // reflect (no edge repeat)
      s = (s >= N) ? (2 * N - 2 - s) : s;
      float v = x[s];
      aL = fmaf(DLO[i], v, aL);
      aH = fmaf(DHI[i], v, aH);
    }
    lo[m] = aL; hi[m] = aH;
  }
}

// Fused M-build + W2-build.
// grid (64, 4), 256 threads. blockIdx.x = k, blockIdx.y = 16-wide tp slice.
// Threads 0-63 compute M = DWT(I_64) (84x64) straight into LDS (one wave,
// ~1120 fully-unrolled FMAs) while the whole block concurrently stages
// conv_w[k]; this removes the old 1-block build_M launch + global round-trip.
// W2[k][tp*64+hw] = sum_t M[t][tp] * conv_w[k][t][hw], rounded to bf16.
__global__ __launch_bounds__(256) void build_w2_fused(
    const float* __restrict__ cw, unsigned short* __restrict__ W2) {
  __shared__ float Ml[84 * 64];
  __shared__ float Cl[84 * 64];
  const int k = blockIdx.x;
  const int tid = threadIdx.x;

  if (tid < 64) {  // column tid of M = DWT(e_tid)
    const int i = tid;
    float sig[64];
#pragma unroll
    for (int t = 0; t < 64; ++t) sig[t] = (t == i) ? 1.f : 0.f;
    float lo1[35], hi1[35], lo2[21], hi2[21], lo3[14], hi3[14];
    afb<64, 35>(sig, lo1, hi1);
    afb<35, 21>(lo1, lo2, hi2);
    afb<21, 14>(lo2, lo3, hi3);
#pragma unroll
    for (int t = 0; t < 14; ++t) Ml[t * 64 + i] = lo3[t];
#pragma unroll
    for (int t = 0; t < 35; ++t) Ml[(14 + t) * 64 + i] = hi1[t];
#pragma unroll
    for (int t = 0; t < 21; ++t) Ml[(49 + t) * 64 + i] = hi2[t];
#pragma unroll
    for (int t = 0; t < 14; ++t) Ml[(70 + t) * 64 + i] = hi3[t];
  }
  const float* cwk = cw + (size_t)k * (84 * 64);
  for (int idx = tid; idx < 84 * 64; idx += 256) Cl[idx] = cwk[idx];
  __syncthreads();

  const int tp  = blockIdx.y * 16 + (tid >> 4);
  const int hw0 = (tid & 15) * 4;
  float a0 = 0.f, a1 = 0.f, a2 = 0.f, a3 = 0.f;
#pragma unroll 4
  for (int t = 0; t < 84; ++t) {
    const float mv = Ml[t * 64 + tp];
    const float4 cv = *(const float4*)&Cl[t * 64 + hw0];
    a0 = fmaf(mv, cv.x, a0);
    a1 = fmaf(mv, cv.y, a1);
    a2 = fmaf(mv, cv.z, a2);
    a3 = fmaf(mv, cv.w, a3);
  }
  uint2 pk;
  pk.x = (unsigned)f2bf_rne(a0) | ((unsigned)f2bf_rne(a1) << 16);
  pk.y = (unsigned)f2bf_rne(a2) | ((unsigned)f2bf_rne(a3) << 16);
  *(uint2*)(W2 + (size_t)k * 4096 + tp * 64 + hw0) = pk;
}

// Streaming GEMM: out[8192][64] = leaky(A[8192][4096] * W2[64][4096]^T + b)
// BM=16, 256 threads (4 waves), grid 512 -> 2 blocks/CU (LDS 42.5 KB/block,
// 85 KB for two). Two independent barrier domains per CU: one block's
// MFMA/load phase covers the other's s_barrier wait, and per-CU outstanding
// global-load bytes double vs the old 512-thread 1-block/CU layout.
#define BM 16
#define BN 64
#define BK 128
#define LDK 136   // +8 bf16 pad: frag-read row stride 272B -> 2-way bank alias (free)
#define NITER 32  // 4096 / BK

__global__ __launch_bounds__(256) void gemm_kernel(
    const float* __restrict__ A, const unsigned short* __restrict__ W2,
    const float* __restrict__ bias, float* __restrict__ out) {
  __shared__ alignas(16) short As[2][BM * LDK];   //  8704 B
  __shared__ alignas(16) short Bs[2][BN * LDK];   // 34816 B  (total 42.5 KB)

  const int tid = threadIdx.x;
  const int b0 = blockIdx.x * BM;                 // 512 * 16 = 8192 rows

  // staging maps: 256 threads cover 16x128 fp32 A (8 floats/thread) and
  // 64x128 bf16 B (32 bf16/thread)
  const int ar = tid >> 4;             // 0..15  (A row in tile)
  const int ac = (tid & 15) * 8;       // 0..120 (A col in chunk, 8 floats)
  const int bn = tid >> 2;             // 0..63  (W2 row)
  const int bc = (tid & 3) * 32;       // 0..96  (32 bf16)

  const float* aptr = A + (size_t)(b0 + ar) * 4096 + ac;
  const unsigned short* bptr = W2 + (size_t)bn * 4096 + bc;

  // mfma tile assignment: 4 waves -> 1 mtile x 4 ntiles of 16x16
  const int lane = tid & 63;
  const int wave = tid >> 6;           // 0..3 = ntile
  const int frow = lane & 15;
  const int fk = (lane >> 4) * 8;

  floatx4 acc = {0.f, 0.f, 0.f, 0.f};

  // depth-2 register prefetch (chunks 0 and 1)
  float4 a0_0, a1_0, a0_1, a1_1;
  uint4  bq_0[4], bq_1[4];
  a0_0 = *(const float4*)(aptr + 0);
  a1_0 = *(const float4*)(aptr + 4);
  a0_1 = *(const float4*)(aptr + BK);
  a1_1 = *(const float4*)(aptr + BK + 4);
#pragma unroll
  for (int j = 0; j < 4; ++j) {
    bq_0[j] = *(const uint4*)(bptr + j * 8);
    bq_1[j] = *(const uint4*)(bptr + BK + j * 8);
  }

  // Raw barrier: lgkmcnt(0) orders LDS writes, but vmcnt is NOT drained, so
  // the depth-2 global prefetches stay in flight across the barrier (the
  // m97 vmcnt(0)-at-__syncthreads stall would cap HBM utilization here).
#define GSTEP(S, I)                                                          \
  do {                                                                       \
    shortx8 av;                                                              \
    av[0] = (short)f2bf_rne(a0_##S.x); av[1] = (short)f2bf_rne(a0_##S.y);    \
    av[2] = (short)f2bf_rne(a0_##S.z); av[3] = (short)f2bf_rne(a0_##S.w);    \
    av[4] = (short)f2bf_rne(a1_##S.x); av[5] = (short)f2bf_rne(a1_##S.y);    \
    av[6] = (short)f2bf_rne(a1_##S.z); av[7] = (short)f2bf_rne(a1_##S.w);    \
    *(shortx8*)&As[S][ar * LDK + ac] = av;                                   \
    *(uint4*)&Bs[S][bn * LDK + bc] = bq_##S[0];                              \
    *(uint4*)&Bs[S][bn * LDK + bc + 8] = bq_##S[1];                          \
    *(uint4*)&Bs[S][bn * LDK + bc + 16] = bq_##S[2];                         \
    *(uint4*)&Bs[S][bn * LDK + bc + 24] = bq_##S[3];                         \
    __asm__ __volatile__("s_waitcnt lgkmcnt(0)\n\ts_barrier" ::: "memory");  \
    if ((I) + 2 < NITER) {                                                   \
      const int c2 = ((I) + 2) * BK;                                         \
      a0_##S = *(const float4*)(aptr + c2);                                  \
      a1_##S = *(const float4*)(aptr + c2 + 4);                              \
      _Pragma("unroll")                                                      \
      for (int j = 0; j < 4; ++j) {                                          \
        bq_##S[j] = *(const uint4*)(bptr + c2 + j * 8);                      \
      }                                                                      \
    }                                                                        \
    _Pragma("unroll")                                                        \
    for (int kk = 0; kk < 4; ++kk) {                                         \
      shortx8 af = *(const shortx8*)&As[S][frow * LDK + kk * 32 + fk];       \
      shortx8 bf = *(const shortx8*)&Bs[S][(wave * 16 + frow) * LDK + kk * 32 + fk]; \
      acc = __builtin_amdgcn_mfma_f32_16x16x32_bf16(af, bf, acc, 0, 0, 0);   \
    }                                                                        \
  } while (0)

  for (int i = 0; i < NITER; i += 2) {
    GSTEP(0, i);
    GSTEP(1, i + 1);
  }
#undef GSTEP

  // epilogue: D layout col = lane&15 (n), row = (lane>>4)*4 + r (m)
  const int ocol = wave * 16 + (lane & 15);
  const int orow0 = b0 + (lane >> 4) * 4;
  const float bv = bias[ocol];
#pragma unroll
  for (int r = 0; r < 4; ++r) {
    float v = acc[r] + bv;
    out[(size_t)(orow0 + r) * 64 + ocol] = (v >= 0.f) ? v : 1.0e-3f * v;
  }
}

extern "C" void kernel_launch(void* const* d_in, const int* in_sizes, int n_in,
                              void* d_out, int out_size, void* d_ws, size_t ws_size,
                              hipStream_t stream) {
  const float* x      = (const float*)d_in[0];  // [8192,1,64,8,8]
  const float* conv_w = (const float*)d_in[1];  // [64,84,8,8]
  const float* conv_b = (const float*)d_in[2];  // [64]
  float* out = (float*)d_out;                   // [8192,64]

  unsigned short* W2 = (unsigned short*)d_ws;   // 64*4096 bf16 = 512 KB

  build_w2_fused<<<dim3(64, 4), 256, 0, stream>>>(conv_w, W2);
  gemm_kernel<<<512, 256, 0, stream>>>(x, W2, conv_b, out);
}

// Round 3
// 212.343 us; speedup vs baseline: 1.2506x; 1.2506x over previous
//
#include <hip/hip_runtime.h>

typedef __attribute__((ext_vector_type(4))) float floatx4;
typedef __attribute__((ext_vector_type(8))) short shortx8;

// db4 analysis filters, TRUE-convolution orientation:
// y[m] = sum_i F[i] * xp[2m + 7 - i]  (xp reflect-padded, pl = 6 at every level)
__device__ __constant__ float DLO[8] = {
    -0.010597401784997278f, 0.032883011666982945f,
     0.030841381835986965f, -0.18703481171888114f,
    -0.02798376941698385f,  0.6308807679295904f,
     0.7148465705525415f,   0.23037781330885523f};
__device__ __constant__ float DHI[8] = {
    -0.23037781330885523f,  0.7148465705525415f,
    -0.6308807679295904f,  -0.02798376941698385f,
     0.18703481171888114f,  0.030841381835986965f,
     0.032883011666982945f, -0.010597401784997278f};

__device__ __forceinline__ unsigned short f2bf_rne(float f) {
  unsigned u = __builtin_bit_cast(unsigned, f);
  unsigned r = (u + 0x7FFFu + ((u >> 16) & 1u)) >> 16;
  return (unsigned short)r;
}

// One analysis filter-bank level. pl (left reflect pad) == 6 for n in {64,35,21}.
template <int N, int OUT>
__device__ __forceinline__ void afb(const float* x, float* lo, float* hi) {
#pragma unroll
  for (int m = 0; m < OUT; ++m) {
    float aL = 0.f, aH = 0.f;
#pragma unroll
    for (int i = 0; i < 8; ++i) {
      int s = 2 * m + 1 - i;              // 2m + 7 - i - 6
      s = (s < 0) ? -s : s;               // reflect (no edge repeat)
      s = (s >= N) ? (2 * N - 2 - s) : s;
      float v = x[s];
      aL = fmaf(DLO[i], v, aL);
      aH = fmaf(DHI[i], v, aH);
    }
    lo[m] = aL; hi[m] = aH;
  }
}

// Fused M-build + W2-build (unchanged from round 2 — passed).
// grid (64, 4), 256 threads. blockIdx.x = k, blockIdx.y = 16-wide tp slice.
// W2[k][tp*64+hw] = sum_t M[t][tp] * conv_w[k][t][hw], rounded to bf16.
__global__ __launch_bounds__(256) void build_w2_fused(
    const float* __restrict__ cw, unsigned short* __restrict__ W2) {
  __shared__ float Ml[84 * 64];
  __shared__ float Cl[84 * 64];
  const int k = blockIdx.x;
  const int tid = threadIdx.x;

  if (tid < 64) {  // column tid of M = DWT(e_tid)
    const int i = tid;
    float sig[64];
#pragma unroll
    for (int t = 0; t < 64; ++t) sig[t] = (t == i) ? 1.f : 0.f;
    float lo1[35], hi1[35], lo2[21], hi2[21], lo3[14], hi3[14];
    afb<64, 35>(sig, lo1, hi1);
    afb<35, 21>(lo1, lo2, hi2);
    afb<21, 14>(lo2, lo3, hi3);
#pragma unroll
    for (int t = 0; t < 14; ++t) Ml[t * 64 + i] = lo3[t];
#pragma unroll
    for (int t = 0; t < 35; ++t) Ml[(14 + t) * 64 + i] = hi1[t];
#pragma unroll
    for (int t = 0; t < 21; ++t) Ml[(49 + t) * 64 + i] = hi2[t];
#pragma unroll
    for (int t = 0; t < 14; ++t) Ml[(70 + t) * 64 + i] = hi3[t];
  }
  const float* cwk = cw + (size_t)k * (84 * 64);
  for (int idx = tid; idx < 84 * 64; idx += 256) Cl[idx] = cwk[idx];
  __syncthreads();

  const int tp  = blockIdx.y * 16 + (tid >> 4);
  const int hw0 = (tid & 15) * 4;
  float a0 = 0.f, a1 = 0.f, a2 = 0.f, a3 = 0.f;
#pragma unroll 4
  for (int t = 0; t < 84; ++t) {
    const float mv = Ml[t * 64 + tp];
    const float4 cv = *(const float4*)&Cl[t * 64 + hw0];
    a0 = fmaf(mv, cv.x, a0);
    a1 = fmaf(mv, cv.y, a1);
    a2 = fmaf(mv, cv.z, a2);
    a3 = fmaf(mv, cv.w, a3);
  }
  uint2 pk;
  pk.x = (unsigned)f2bf_rne(a0) | ((unsigned)f2bf_rne(a1) << 16);
  pk.y = (unsigned)f2bf_rne(a2) | ((unsigned)f2bf_rne(a3) << 16);
  *(uint2*)(W2 + (size_t)k * 4096 + tp * 64 + hw0) = pk;
}

// ---- GEMM: barrier-free split-K, direct global->register fragments ----
// out[8192][64] = leaky(A[8192][4096] x W2[64][4096]^T + b)
// grid 512, 512 threads (8 waves). Block = one 16-row m-tile; wave w owns
// K-slice [w*512, (w+1)*512) and all 4 n-tiles (A read ONCE from HBM, W2
// fragments straight from L2). No LDS staging, no barriers in the K loop —
// the round-0/2 counters showed the per-chunk s_barrier+lgkmcnt(0) domain
// left MFMA/VALU/HBM all <3% busy. One __syncthreads for the final 8-way
// partial reduction in LDS.

#define NCH 16   // K32 chunks per wave (512 K elements)

__global__ __launch_bounds__(512) void gemm_kernel(
    const float* __restrict__ A, const unsigned short* __restrict__ W2,
    const float* __restrict__ bias, float* __restrict__ out) {
  __shared__ floatx4 red[8 * 4 * 64];  // 32 KB: [wave][ntile][lane]

  const int tid  = threadIdx.x;
  const int lane = tid & 63;
  const int wave = tid >> 6;            // 0..7 = K-slice
  const int frow = lane & 15;
  const int fk   = (lane >> 4) * 8;     // 0,8,16,24
  const int m0   = blockIdx.x * 16;     // 512 * 16 = 8192 rows
  const int k0   = wave * (NCH * 32);

  // A fragment source: row m0+frow, cols k0+fk+... (128 B per row per chunk,
  // cache-line aligned; each element read by exactly one lane in the grid)
  const float* aptr = A + (size_t)(m0 + frow) * 4096 + k0 + fk;
  // B fragment source: row nt*16+frow, same cols (64 B per row, L2-resident)
  const unsigned short* bptr = W2 + (size_t)frow * 4096 + k0 + fk;

  floatx4 acc0 = {0.f, 0.f, 0.f, 0.f};
  floatx4 acc1 = acc0, acc2 = acc0, acc3 = acc0;

  // depth-2 register prefetch (chunks 0 and 1)
  float4 alo_0, ahi_0, alo_1, ahi_1;
  uint4  bq_0[4], bq_1[4];
  alo_0 = *(const float4*)(aptr + 0);
  ahi_0 = *(const float4*)(aptr + 4);
  alo_1 = *(const float4*)(aptr + 32);
  ahi_1 = *(const float4*)(aptr + 36);
#pragma unroll
  for (int nt = 0; nt < 4; ++nt) {
    bq_0[nt] = *(const uint4*)(bptr + nt * 65536);
    bq_1[nt] = *(const uint4*)(bptr + nt * 65536 + 32);
  }

#define STEP(S, C)                                                           \
  do {                                                                       \
    shortx8 af;                                                              \
    af[0] = (short)f2bf_rne(alo_##S.x); af[1] = (short)f2bf_rne(alo_##S.y);  \
    af[2] = (short)f2bf_rne(alo_##S.z); af[3] = (short)f2bf_rne(alo_##S.w);  \
    af[4] = (short)f2bf_rne(ahi_##S.x); af[5] = (short)f2bf_rne(ahi_##S.y);  \
    af[6] = (short)f2bf_rne(ahi_##S.z); af[7] = (short)f2bf_rne(ahi_##S.w);  \
    acc0 = __builtin_amdgcn_mfma_f32_16x16x32_bf16(                          \
        af, __builtin_bit_cast(shortx8, bq_##S[0]), acc0, 0, 0, 0);          \
    acc1 = __builtin_amdgcn_mfma_f32_16x16x32_bf16(                          \
        af, __builtin_bit_cast(shortx8, bq_##S[1]), acc1, 0, 0, 0);          \
    acc2 = __builtin_amdgcn_mfma_f32_16x16x32_bf16(                          \
        af, __builtin_bit_cast(shortx8, bq_##S[2]), acc2, 0, 0, 0);          \
    acc3 = __builtin_amdgcn_mfma_f32_16x16x32_bf16(                          \
        af, __builtin_bit_cast(shortx8, bq_##S[3]), acc3, 0, 0, 0);          \
    if ((C) + 2 < NCH) {                                                     \
      const int cc = ((C) + 2) * 32;                                         \
      alo_##S = *(const float4*)(aptr + cc);                                 \
      ahi_##S = *(const float4*)(aptr + cc + 4);                             \
      _Pragma("unroll")                                                      \
      for (int nt = 0; nt < 4; ++nt)                                         \
        bq_##S[nt] = *(const uint4*)(bptr + nt * 65536 + cc);                \
    }                                                                        \
  } while (0)

#pragma unroll 2
  for (int c = 0; c < NCH; c += 2) {
    STEP(0, c);
    STEP(1, c + 1);
  }
#undef STEP

  // dump partials: [wave][nt][lane] of floatx4 (conflict-free b128 writes)
  red[(wave * 4 + 0) * 64 + lane] = acc0;
  red[(wave * 4 + 1) * 64 + lane] = acc1;
  red[(wave * 4 + 2) * 64 + lane] = acc2;
  red[(wave * 4 + 3) * 64 + lane] = acc3;
  __syncthreads();

  // 8-way reduce + bias + leaky + store. 512 threads x 2 outputs.
  // D layout: col = lane&15, row = (lane>>4)*4 + r.
  const float* redf = (const float*)red;
  for (int o = tid; o < 1024; o += 512) {
    const int m  = o >> 6;
    const int n  = o & 63;
    const int l  = ((m >> 2) << 4) | (n & 15);
    const int r  = m & 3;
    const int nt = n >> 4;
    float s = bias[n];
#pragma unroll
    for (int w = 0; w < 8; ++w)
      s += redf[(((w * 4 + nt) * 64 + l) << 2) | r];
    out[(size_t)(m0 + m) * 64 + n] = (s >= 0.f) ? s : 1.0e-3f * s;
  }
}

extern "C" void kernel_launch(void* const* d_in, const int* in_sizes, int n_in,
                              void* d_out, int out_size, void* d_ws, size_t ws_size,
                              hipStream_t stream) {
  const float* x      = (const float*)d_in[0];  // [8192,1,64,8,8]
  const float* conv_w = (const float*)d_in[1];  // [64,84,8,8]
  const float* conv_b = (const float*)d_in[2];  // [64]
  float* out = (float*)d_out;                   // [8192,64]

  unsigned short* W2 = (unsigned short*)d_ws;   // 64*4096 bf16 = 512 KB

  build_w2_fused<<<dim3(64, 4), 256, 0, stream>>>(conv_w, W2);
  gemm_kernel<<<512, 512, 0, stream>>>(x, W2, conv_b, out);
}